// Round 8
// baseline (240.571 us; speedup 1.0000x reference)
//
#include <hip/hip_runtime.h>
#include <math.h>

#define TSEQ  2048
#define BATCH 2
#define NH    16
#define HD    64
#define CDIM  1024
#define N3C   3072
#define EPSY  1e-6f

typedef unsigned short u16;
typedef unsigned int u32;
typedef __attribute__((ext_vector_type(2))) unsigned int u32x2;
typedef __attribute__((ext_vector_type(8))) short bf16x8;
typedef __attribute__((ext_vector_type(4))) float f32x4;

#define MFMA16(a, b, c) __builtin_amdgcn_mfma_f32_16x16x32_bf16(a, b, c, 0, 0, 0)

__device__ __forceinline__ u16 f2bf(float f) {
    unsigned u = __float_as_uint(f);
    return (u16)((u + 0x7fffu + ((u >> 16) & 1u)) >> 16);
}
// packed f32x2 -> bf16x2 (RNE, identical to f2bf) in ONE VALU instruction
__device__ __forceinline__ u32 cvtpk_bf16(float lo, float hi) {
    u32 r;
    asm("v_cvt_pk_bf16_f32 %0, %1, %2" : "=v"(r) : "v"(lo), "v"(hi));
    return r;
}
__device__ __forceinline__ void gload16(const void* g, void* l) {
    __builtin_amdgcn_global_load_lds(
        (const __attribute__((address_space(1))) unsigned int*)g,
        (__attribute__((address_space(3))) unsigned int*)l, 16, 0, 0);
}

// ---------------------------------------------------------------------------
// Fused prep: one launch replaces rope_init/colsq/convert_rows/convert_wT x2.
__global__ __launch_bounds__(256) void prep_kernel(
    const float* __restrict__ x, const float* __restrict__ wa,
    const float* __restrict__ wp, u16* __restrict__ Ahi,
    u16* __restrict__ Wthi, u16* __restrict__ Wphi,
    float* __restrict__ ksq, float* __restrict__ xsq,
    float* __restrict__ osq, float2* __restrict__ ropeSC) {
    __shared__ float smem[64 * 68];
    int bid = blockIdx.x, tid = threadIdx.x;

    if (bid < 4096) {                      // ---- convert_rows
        int lane = tid & 63, wv = tid >> 6;
        size_t base = (size_t)bid * CDIM + tid * 4;
        float4 v = *(const float4*)(x + base);
        ushort4 hi;
        hi.x = f2bf(v.x); hi.y = f2bf(v.y); hi.z = f2bf(v.z); hi.w = f2bf(v.w);
        *(ushort4*)(Ahi + base) = hi;
        float s = v.x * v.x + v.y * v.y + v.z * v.z + v.w * v.w;
        #pragma unroll
        for (int off = 32; off; off >>= 1) s += __shfl_down(s, off, 64);
        if (lane == 0) smem[wv] = s;
        __syncthreads();
        if (tid == 0) xsq[bid] = smem[0] + smem[1] + smem[2] + smem[3];
    } else if (bid < 5120) {               // ---- transpose+convert weights
        const float* W; u16* Whi; int K, N, bx, by;
        if (bid < 4864) {
            int t = bid - 4096; W = wa; Whi = Wthi; K = CDIM; N = N3C;
            bx = t % 48; by = t / 48;
        } else {
            int t = bid - 4864; W = wp; Whi = Wphi; K = CDIM; N = CDIM;
            bx = t % 16; by = t / 16;
        }
        int k0 = by * 64, n0 = bx * 64;
        int r = tid >> 4, c4 = (tid & 15) * 4;
        #pragma unroll
        for (int i = 0; i < 4; ++i) {
            int k = k0 + r + i * 16;
            float4 v = *(const float4*)(W + (size_t)k * N + n0 + c4);
            *(float4*)&smem[(r + i * 16) * 68 + c4] = v;
        }
        __syncthreads();
        int n = tid >> 4, k4 = (tid & 15) * 4;
        #pragma unroll
        for (int i = 0; i < 4; ++i) {
            int nn = n + i * 16;
            ushort4 hi;
            hi.x = f2bf(smem[(k4 + 0) * 68 + nn]);
            hi.y = f2bf(smem[(k4 + 1) * 68 + nn]);
            hi.z = f2bf(smem[(k4 + 2) * 68 + nn]);
            hi.w = f2bf(smem[(k4 + 3) * 68 + nn]);
            *(ushort4*)(Whi + (size_t)(n0 + nn) * K + k0 + k4) = hi;
        }
    } else if (bid < 5184) {               // ---- colsq
        int b2 = bid - 5120;
        int c = tid & 63, kq = tid >> 6;
        const float* W; int N, col, outoff;
        if (b2 < 48) { W = wa; N = N3C;  col = b2 * 64 + c;        outoff = 0;   }
        else         { W = wp; N = CDIM; col = (b2 - 48) * 64 + c; outoff = N3C; }
        float s = 0.f;
        int i0 = kq * 256;
        #pragma unroll 4
        for (int i = i0; i < i0 + 256; ++i) {
            float v = W[(size_t)i * N + col];
            s = fmaf(v, v, s);
        }
        smem[tid] = s;
        __syncthreads();
        if (kq == 0)
            ksq[outoff + col] = smem[c] + smem[64 + c] + smem[128 + c] + smem[192 + c];
    } else {                               // ---- rope table + osq zero
        int idx = (bid - 5184) * 256 + tid;   // [0, 65536)
        if (idx < BATCH * TSEQ) osq[idx] = 0.f;
        int t = idx >> 5, j = idx & 31;
        float inv = exp2f(-(float)j * 0.4152410118609203f);
        float ang = (float)t * inv;
        ropeSC[idx] = make_float2(cosf(ang), sinf(ang));
    }
}

// ---------------------------------------------------------------------------
// GEMM1: single-bf16 MFMA, yat epilogue + rotary table + bf16 pack.
// 128x128 / 256-thread / 4-wave structure + XCD-chunked swizzle (R7,
// FETCH 38->29.5 MB). THIS ROUND (T4 counted-vmcnt): triple-buffered LDS,
// 2-ahead prefetch, raw s_barrier with s_waitcnt vmcnt(8) -- tile kt+2's
// 8 loads stay IN FLIGHT across the barrier instead of draining to 0
// every iteration (the ~500cyc/iter stall R7 exposed). Waitcnt ledger:
// at end of iter kt we need tile kt+1's loads done; loads newer than
// those = the 8 for kt+2 (if issued) -> vmcnt(8), else vmcnt(0).
// LDS 48 KB -> cap 3 blocks/CU == grid's exact 3/CU (no occupancy loss).
__global__ __launch_bounds__(256, 4) void gemm1_fused(
    const u16* __restrict__ Ah, const u16* __restrict__ Bh,
    const float* __restrict__ bias, const float* __restrict__ rowsq,
    const float* __restrict__ colsq, const float* __restrict__ alphap,
    const float2* __restrict__ ropeSC,
    u16* __restrict__ Qb, u16* __restrict__ Kb, u16* __restrict__ Vt) {
    constexpr int BK = 32;
    const int K = CDIM;
    __shared__ u16 Ash[3][128 * BK], Bsh[3][128 * BK];
    int tid = threadIdx.x;
    int lane = tid & 63, wv = tid >> 6;
    int quad = lane >> 4, l15 = lane & 15;
    int wr = wv >> 1, wc = wv & 1;

    // XCD-chunked swizzle: 768 blocks = 8 XCD x 96 (4 bm-bands x 24 bn).
    int lin = blockIdx.x + blockIdx.y * 24;
    int swz = (lin & 7) * 96 + (lin >> 3);
    int bn = (swz % 24) * 128;
    int bm = (swz / 24) * 128;

    int rsub = lane >> 2;
    int lc8 = (lane & 3) * 8;
    int gc8 = (((lane & 3) - (rsub >> 1)) & 3) * 8;
    int pf8 = ((quad + (l15 >> 1)) & 3) * 8;

    f32x4 acc[4][4];
    #pragma unroll
    for (int i = 0; i < 4; ++i)
        #pragma unroll
        for (int j = 0; j < 4; ++j) acc[i][j] = (f32x4){0.f, 0.f, 0.f, 0.f};

    auto STAGE = [&](int buf, int kt) {
        #pragma unroll
        for (int i = 0; i < 2; ++i) {
            int r = i * 64 + wv * 16 + rsub;
            gload16(Ah + (size_t)(bm + r) * K + kt + gc8, &Ash[buf][r * BK + lc8]);
            gload16(Bh + (size_t)(bn + r) * K + kt + gc8, &Bsh[buf][r * BK + lc8]);
        }
    };

    // prologue: stage tiles 0 and 1; wait only tile 0 (vmcnt(8): tile 1's
    // 8 loads stay outstanding), then cross-wave barrier.
    STAGE(0, 0);
    STAGE(1, BK);
    asm volatile("s_waitcnt vmcnt(8) lgkmcnt(0)" ::: "memory");
    __builtin_amdgcn_s_barrier();
    __builtin_amdgcn_sched_barrier(0);
    int cur = 0;

    for (int kt = 0; kt < K; kt += BK) {
        int nx2 = cur + 2; if (nx2 >= 3) nx2 -= 3;
        if (kt + 2 * BK < K) STAGE(nx2, kt + 2 * BK);
        bf16x8 fah[4], fbh[4];
        #pragma unroll
        for (int i = 0; i < 4; ++i)
            fah[i] = *(const bf16x8*)&Ash[cur][(wr * 64 + i * 16 + l15) * BK + pf8];
        #pragma unroll
        for (int j = 0; j < 4; ++j)
            fbh[j] = *(const bf16x8*)&Bsh[cur][(wc * 64 + j * 16 + l15) * BK + pf8];
        #pragma unroll
        for (int i = 0; i < 4; ++i)
            #pragma unroll
            for (int j = 0; j < 4; ++j)
                acc[i][j] = MFMA16(fah[i], fbh[j], acc[i][j]);
        // need tile kt+1 landed (all waves); tile kt+2's loads keep flying.
        if (kt + 2 * BK < K)
            asm volatile("s_waitcnt vmcnt(8) lgkmcnt(0)" ::: "memory");
        else
            asm volatile("s_waitcnt vmcnt(0) lgkmcnt(0)" ::: "memory");
        __builtin_amdgcn_s_barrier();
        __builtin_amdgcn_sched_barrier(0);
        ++cur; if (cur >= 3) cur -= 3;
    }

    float alpha = alphap[0];
    float scale = powf(sqrtf((float)N3C) / logf(1.0f + (float)N3C), alpha);
    int segc0 = bn + wc * 64;          // wave-uniform
    int seg = segc0 >> 10;             // 0=Q 1=K 2=V
    int h = (segc0 >> 6) & 15;
    int bglob = bm >> 11;
    int bh = bglob * NH + h;

    if (seg < 2) {
        u16* dst = (seg == 0) ? Qb : Kb;
        // Q: 1/sqrt(64) * log2(e) = 0.125 * 1.4426950408889634
        float qs = (seg == 0) ? 0.18033688011112043f : 1.0f;
        #pragma unroll
        for (int i = 0; i < 4; ++i) {
            int tb = bm + wr * 64 + i * 16 + quad * 4;
            #pragma unroll
            for (int r = 0; r < 4; ++r) {
                int row = tb + r;
                int t = row & (TSEQ - 1);
                float rs = rowsq[row];
                float y[4];
                #pragma unroll
                for (int j = 0; j < 4; ++j) {
                    int col = segc0 + j * 16 + l15;
                    float dot = acc[i][j][r];
                    float dist = rs + colsq[col] - 2.0f * dot + EPSY;
                    y[j] = dot * dot / dist * scale + bias[col];
                }
                float2 sc0 = ropeSC[t * 32 + l15];
                float2 sc1 = ropeSC[t * 32 + 16 + l15];
                float c0 = sc0.x, s0 = sc0.y, c1 = sc1.x, s1 = sc1.y;
                size_t ob = ((size_t)bh * TSEQ + t) * HD;
                dst[ob + l15]      = f2bf((y[0] * c0 - y[2] * s0) * qs);
                dst[ob + 16 + l15] = f2bf((y[1] * c1 - y[3] * s1) * qs);
                dst[ob + 32 + l15] = f2bf((y[2] * c0 + y[0] * s0) * qs);
                dst[ob + 48 + l15] = f2bf((y[3] * c1 + y[1] * s1) * qs);
            }
        }
    } else {
        #pragma unroll
        for (int i = 0; i < 4; ++i) {
            int tb = bm + wr * 64 + i * 16 + quad * 4;
            int t0 = tb & (TSEQ - 1);
            #pragma unroll
            for (int j = 0; j < 4; ++j) {
                int col = segc0 + j * 16 + l15;
                int d = j * 16 + l15;
                float cs = colsq[col], bi = bias[col];
                ushort4 pk;
                u16* pp = (u16*)&pk;
                #pragma unroll
                for (int r = 0; r < 4; ++r) {
                    float dot = acc[i][j][r];
                    float dist = rowsq[tb + r] + cs - 2.0f * dot + EPSY;
                    pp[r] = f2bf(dot * dot / dist * scale + bi);
                }
                *(ushort4*)(Vt + ((size_t)bh * HD + d) * TSEQ + t0) = pk;
            }
        }
    }
}

// ---------------------------------------------------------------------------
// GEMM2: single-bf16 MFMA + yat epilogue, fp32 out. 128x64 tile, swizzled,
// double-buffered. XCD-chunked swizzle (512 blocks, 64/XCD = 4 bm x 16 bn).
__global__ __launch_bounds__(256, 4) void gemm_yat_mfma(
    const u16* __restrict__ Ah, const u16* __restrict__ Bh,
    const float* __restrict__ bias, const float* __restrict__ rowsq,
    const float* __restrict__ colsq, const float* __restrict__ alphap,
    float* __restrict__ outp, int M, int N, int K, float outf) {
    constexpr int BM = 128, BN = 64, BK = 32;
    __shared__ u16 Ash[2][BM * BK], Bsh[2][BN * BK];
    int tid = threadIdx.x;
    int lane = tid & 63, wv = tid >> 6;
    int quad = lane >> 4, l15 = lane & 15;
    int lin = blockIdx.x + blockIdx.y * 16;
    int swz = (lin & 7) * 64 + (lin >> 3);
    int bn = (swz % 16) * BN;
    int bm = (swz / 16) * BM;
    int rsub = lane >> 2;
    int lc8 = (lane & 3) * 8;
    int gc8 = (((lane & 3) - (rsub >> 1)) & 3) * 8;
    int pf8 = ((quad + (l15 >> 1)) & 3) * 8;

    f32x4 acc[2][4];
    #pragma unroll
    for (int i = 0; i < 2; ++i)
        #pragma unroll
        for (int j = 0; j < 4; ++j) acc[i][j] = (f32x4){0.f, 0.f, 0.f, 0.f};

    auto STAGE = [&](int buf, int kt) {
        #pragma unroll
        for (int i = 0; i < 2; ++i) {
            int r = i * 64 + wv * 16 + rsub;
            gload16(Ah + (size_t)(bm + r) * K + kt + gc8, &Ash[buf][r * BK + lc8]);
        }
        {
            int r = wv * 16 + rsub;
            gload16(Bh + (size_t)(bn + r) * K + kt + gc8, &Bsh[buf][r * BK + lc8]);
        }
    };

    STAGE(0, 0);
    __syncthreads();                    // buf0 ready
    int cur = 0;

    for (int kt = 0; kt < K; kt += BK) {
        if (kt + BK < K) STAGE(cur ^ 1, kt + BK);
        bf16x8 fah[2], fbh[4];
        #pragma unroll
        for (int i = 0; i < 2; ++i)
            fah[i] = *(const bf16x8*)&Ash[cur][(wv * 32 + i * 16 + l15) * BK + pf8];
        #pragma unroll
        for (int j = 0; j < 4; ++j)
            fbh[j] = *(const bf16x8*)&Bsh[cur][(j * 16 + l15) * BK + pf8];
        #pragma unroll
        for (int i = 0; i < 2; ++i)
            #pragma unroll
            for (int j = 0; j < 4; ++j)
                acc[i][j] = MFMA16(fah[i], fbh[j], acc[i][j]);
        __syncthreads();
        cur ^= 1;
    }

    float alpha = alphap[0];
    float scale = powf(sqrtf(outf) / logf(1.0f + outf), alpha);
    #pragma unroll
    for (int j = 0; j < 4; ++j) {
        int col = bn + j * 16 + l15;
        float cs = colsq[col], bi = bias[col];
        #pragma unroll
        for (int i = 0; i < 2; ++i) {
            #pragma unroll
            for (int r = 0; r < 4; ++r) {
                int row = bm + wv * 32 + i * 16 + quad * 4 + r;
                float dot = acc[i][j][r];
                float dist = rowsq[row] + cs - 2.0f * dot + EPSY;
                outp[(size_t)row * N + col] = dot * dot / dist * scale + bi;
            }
        }
    }
}

// ---------------------------------------------------------------------------
// S^T bf16 MFMA causal flash attention, fixed-shift softmax, exp2 domain
// (log2e folded into Q scale in gemm1). 512-thread blocks (8 waves, 128
// queries) sharing one K/V staging; waves with fully-masked tiles skip
// compute wave-uniformly but keep barriers. P-redistribution:
// v_permlane32_swap + ds_swizzle. Double-buffered K/V, one barrier/iter,
// setprio kept. grid (32 bh, 16 qblk) = 512 blocks, all co-resident.
__global__ __launch_bounds__(512) void attn_mfma(
    const u16* __restrict__ Qb, const u16* __restrict__ Kb,
    const u16* __restrict__ Vt, u16* __restrict__ Chi,
    float* __restrict__ osq) {
    __shared__ u16 Ksh[2][64 * 64];   // [buf][key][d-chunks, rotated by key]
    __shared__ u16 Vsh[2][64 * 64];   // [buf][d][key-chunks, rotated by d]
    int tid = threadIdx.x;
    int lane = tid & 63, wv = tid >> 6;       // wv in {0..7}
    int quad = lane >> 4, l15 = lane & 15;
    const bool oddq = (quad & 1) != 0;
    int bh = blockIdx.x;
    int b = bh >> 4, h = bh & 15;
    const u16* Qh = Qb + (size_t)bh * TSEQ * HD;
    const u16* Kh = Kb + (size_t)bh * TSEQ * HD;
    const u16* Vh = Vt + (size_t)bh * HD * TSEQ;
    const f32x4 zf = {0.f, 0.f, 0.f, 0.f};

    int qbb = 15 - blockIdx.y;         // longest first; 128-query block
    int qw = qbb * 128 + wv * 16;      // this wave's 16 queries
    int NT = 2 * qbb + 2;              // k-tiles this block needs
    bf16x8 bq0 = *(const bf16x8*)(Qh + (size_t)(qw + l15) * HD + quad * 8);
    bf16x8 bq1 = *(const bf16x8*)(Qh + (size_t)(qw + l15) * HD + 32 + quad * 8);

    f32x4 o[4] = {zf, zf, zf, zf};
    float l = 0.f;

    auto STAGE = [&](int buf, int kt) {
        int k0s = kt * 64;
        int rowi = tid >> 3, ch = tid & 7;    // 512 threads cover 64x8 chunks
        int gk = (ch + rowi) & 7;
        gload16(Kh + (size_t)(k0s + rowi) * HD + gk * 8, &Ksh[buf][tid * 8]);
        gload16(Vh + (size_t)rowi * TSEQ + k0s + gk * 8, &Vsh[buf][tid * 8]);
    };

    STAGE(0, 0);
    __syncthreads();                   // drains vmcnt(0): buf0 ready
    int cur = 0;

    for (int kt = 0; kt < NT; ++kt) {
        int k0 = kt * 64;
        if (kt + 1 < NT) STAGE(cur ^ 1, kt + 1);
        if (k0 <= qw + 15) {           // wave-uniform: skip fully-masked tiles
            const u16* Kc = Ksh[cur];
            const u16* Vc = Vsh[cur];

            f32x4 st[4];
            __builtin_amdgcn_s_setprio(1);
            #pragma unroll
            for (int mt = 0; mt < 4; ++mt) {
                int key = mt * 16 + l15;
                bf16x8 a0 = *(const bf16x8*)&Kc[key * 64 + ((quad - key) & 7) * 8];
                bf16x8 a1 = *(const bf16x8*)&Kc[key * 64 + ((4 + quad - key) & 7) * 8];
                st[mt] = MFMA16(a0, bq0, zf);
                st[mt] = MFMA16(a1, bq1, st[mt]);
            }
            __builtin_amdgcn_s_setprio(0);
            if (k0 + 63 > qw) {        // diagonal tile for this wave
                int q = qw + l15;
                #pragma unroll
                for (int mt = 0; mt < 4; ++mt)
                    #pragma unroll
                    for (int r = 0; r < 4; ++r)
                        if (k0 + mt * 16 + quad * 4 + r > q) st[mt][r] = -1e30f;
            }
            u32 pp[4][2];
            #pragma unroll
            for (int mt = 0; mt < 4; ++mt) {
                float p0 = __builtin_amdgcn_exp2f(st[mt][0]);
                float p1 = __builtin_amdgcn_exp2f(st[mt][1]);
                float p2 = __builtin_amdgcn_exp2f(st[mt][2]);
                float p3 = __builtin_amdgcn_exp2f(st[mt][3]);
                l += (p0 + p1) + (p2 + p3);
                pp[mt][0] = cvtpk_bf16(p0, p1);
                pp[mt][1] = cvtpk_bf16(p2, p3);
            }
            // PV: redistribute P across quads (same l15) with
            // permlane32_swap (cross-half) + ds_swizzle xor-16 (within-half).
            #pragma unroll
            for (int s = 0; s < 2; ++s) {
                u32x2 r0 = __builtin_amdgcn_permlane32_swap(
                    pp[2 * s][0], pp[2 * s + 1][0], false, false);
                u32 sA0 = (u32)__builtin_amdgcn_ds_swizzle((int)r0.x, 0x401F);
                u32 sB0 = (u32)__builtin_amdgcn_ds_swizzle((int)r0.y, 0x401F);
                u32x2 r1 = __builtin_amdgcn_permlane32_swap(
                    pp[2 * s][1], pp[2 * s + 1][1], false, false);
                u32 sA1 = (u32)__builtin_amdgcn_ds_swizzle((int)r1.x, 0x401F);
                u32 sB1 = (u32)__builtin_amdgcn_ds_swizzle((int)r1.y, 0x401F);
                u32 bw0 = oddq ? sB0 : r0.x;
                u32 bw1 = oddq ? sB1 : r1.x;
                u32 bw2 = oddq ? r0.y : sA0;
                u32 bw3 = oddq ? r1.y : sA1;
                bf16x8 bfr;
                *(u32*)&((short*)&bfr)[0] = bw0;
                *(u32*)&((short*)&bfr)[2] = bw1;
                *(u32*)&((short*)&bfr)[4] = bw2;
                *(u32*)&((short*)&bfr)[6] = bw3;
                __builtin_amdgcn_s_setprio(1);
                #pragma unroll
                for (int dt = 0; dt < 4; ++dt) {
                    int d = dt * 16 + l15;
                    bf16x8 av = *(const bf16x8*)&Vc[d * 64 + ((s * 4 + quad - d) & 7) * 8];
                    o[dt] = MFMA16(av, bfr, o[dt]);
                }
                __builtin_amdgcn_s_setprio(0);
            }
        }
        __syncthreads();               // drains stage vmcnt; all waves done
        cur ^= 1;
    }

    // deferred cross-quad l reduction, bf16 write, fused row-sumsq
    l += __shfl_xor(l, 16, 64);
    l += __shfl_xor(l, 32, 64);
    float inv = 1.0f / l;
    int row = (b << 11) + qw + l15;
    float ss = 0.f;
    #pragma unroll
    for (int dt = 0; dt < 4; ++dt) {
        float v0 = o[dt][0] * inv, v1 = o[dt][1] * inv;
        float v2 = o[dt][2] * inv, v3 = o[dt][3] * inv;
        ss += v0 * v0 + v1 * v1 + v2 * v2 + v3 * v3;
        uint2 pk2;
        pk2.x = cvtpk_bf16(v0, v1);
        pk2.y = cvtpk_bf16(v2, v3);
        *(uint2*)(Chi + (size_t)row * CDIM + h * HD + dt * 16 + quad * 4) = pk2;
    }
    ss += __shfl_xor(ss, 16, 64);
    ss += __shfl_xor(ss, 32, 64);
    if (quad == 0) atomicAdd(osq + row, ss);
}

// ---------------------------------------------------------------------------
extern "C" void kernel_launch(void* const* d_in, const int* in_sizes, int n_in,
                              void* d_out, int out_size, void* d_ws, size_t ws_size,
                              hipStream_t stream) {
    const float* x      = (const float*)d_in[0];
    const float* w_attn = (const float*)d_in[2];
    const float* b_attn = (const float*)d_in[3];
    const float* a_attn = (const float*)d_in[4];
    const float* w_proj = (const float*)d_in[5];
    const float* b_proj = (const float*)d_in[6];
    const float* a_proj = (const float*)d_in[7];
    float* outp = (float*)d_out;

    char* ws = (char*)d_ws;
    float* ksq = (float*)(ws);
    float* xsq = (float*)(ws + 16384);
    float* osq = (float*)(ws + 32768);
    char* pA  = ws + 65536;                    // 16.78 MB: Ahi -> Chi
    u16* Ahi = (u16*)pA;
    u16* Chi = (u16*)pA;                       // alias (Ahi dead after GEMM1)
    char* pWt = pA + 16777216;                 // 6.29 MB
    u16* Wthi = (u16*)pWt;
    char* pWp = pWt + 6291456;                 // 2.10 MB
    u16* Wphi = (u16*)pWp;
    char* pQ = pWp + 2097152;                  // 25.17 MB: Qb,Kb,Vt
    u16* Qb = (u16*)pQ;
    u16* Kb = (u16*)(pQ + 8388608);
    u16* Vt = (u16*)(pQ + 16777216);
    float2* ropeSC = (float2*)(pQ + 25165824); // 512 KB

    prep_kernel<<<5440, 256, 0, stream>>>(
        x, w_attn, w_proj, Ahi, Wthi, Wphi, ksq, xsq, osq, ropeSC);
    gemm1_fused<<<dim3(N3C / 128, (BATCH * TSEQ) / 128), 256, 0, stream>>>(
        Ahi, Wthi, b_attn, xsq, ksq, a_attn, ropeSC, Qb, Kb, Vt);
    attn_mfma<<<dim3(BATCH * NH, 16), 512, 0, stream>>>(Qb, Kb, Vt, Chi, osq);
    gemm_yat_mfma<<<dim3(CDIM / 64, (BATCH * TSEQ) / 128), 256, 0, stream>>>(
        Chi, Wphi, b_proj, osq, ksq + N3C, a_proj, outp,
        BATCH * TSEQ, CDIM, CDIM, (float)CDIM);
}

// Round 9
// 222.824 us; speedup vs baseline: 1.0796x; 1.0796x over previous
//
#include <hip/hip_runtime.h>
#include <math.h>

#define TSEQ  2048
#define BATCH 2
#define NH    16
#define HD    64
#define CDIM  1024
#define N3C   3072
#define EPSY  1e-6f

typedef unsigned short u16;
typedef unsigned int u32;
typedef __attribute__((ext_vector_type(2))) unsigned int u32x2;
typedef __attribute__((ext_vector_type(8))) short bf16x8;
typedef __attribute__((ext_vector_type(4))) float f32x4;

#define MFMA16(a, b, c) __builtin_amdgcn_mfma_f32_16x16x32_bf16(a, b, c, 0, 0, 0)

__device__ __forceinline__ u16 f2bf(float f) {
    unsigned u = __float_as_uint(f);
    return (u16)((u + 0x7fffu + ((u >> 16) & 1u)) >> 16);
}
// packed f32x2 -> bf16x2 (RNE, identical to f2bf) in ONE VALU instruction
__device__ __forceinline__ u32 cvtpk_bf16(float lo, float hi) {
    u32 r;
    asm("v_cvt_pk_bf16_f32 %0, %1, %2" : "=v"(r) : "v"(lo), "v"(hi));
    return r;
}
__device__ __forceinline__ void gload16(const void* g, void* l) {
    __builtin_amdgcn_global_load_lds(
        (const __attribute__((address_space(1))) unsigned int*)g,
        (__attribute__((address_space(3))) unsigned int*)l, 16, 0, 0);
}

// ---------------------------------------------------------------------------
// Fused prep: one launch replaces rope_init/colsq/convert_rows/convert_wT x2.
__global__ __launch_bounds__(256) void prep_kernel(
    const float* __restrict__ x, const float* __restrict__ wa,
    const float* __restrict__ wp, u16* __restrict__ Ahi,
    u16* __restrict__ Wthi, u16* __restrict__ Wphi,
    float* __restrict__ ksq, float* __restrict__ xsq,
    float* __restrict__ osq, float2* __restrict__ ropeSC) {
    __shared__ float smem[64 * 68];
    int bid = blockIdx.x, tid = threadIdx.x;

    if (bid < 4096) {                      // ---- convert_rows
        int lane = tid & 63, wv = tid >> 6;
        size_t base = (size_t)bid * CDIM + tid * 4;
        float4 v = *(const float4*)(x + base);
        ushort4 hi;
        hi.x = f2bf(v.x); hi.y = f2bf(v.y); hi.z = f2bf(v.z); hi.w = f2bf(v.w);
        *(ushort4*)(Ahi + base) = hi;
        float s = v.x * v.x + v.y * v.y + v.z * v.z + v.w * v.w;
        #pragma unroll
        for (int off = 32; off; off >>= 1) s += __shfl_down(s, off, 64);
        if (lane == 0) smem[wv] = s;
        __syncthreads();
        if (tid == 0) xsq[bid] = smem[0] + smem[1] + smem[2] + smem[3];
    } else if (bid < 5120) {               // ---- transpose+convert weights
        const float* W; u16* Whi; int K, N, bx, by;
        if (bid < 4864) {
            int t = bid - 4096; W = wa; Whi = Wthi; K = CDIM; N = N3C;
            bx = t % 48; by = t / 48;
        } else {
            int t = bid - 4864; W = wp; Whi = Wphi; K = CDIM; N = CDIM;
            bx = t % 16; by = t / 16;
        }
        int k0 = by * 64, n0 = bx * 64;
        int r = tid >> 4, c4 = (tid & 15) * 4;
        #pragma unroll
        for (int i = 0; i < 4; ++i) {
            int k = k0 + r + i * 16;
            float4 v = *(const float4*)(W + (size_t)k * N + n0 + c4);
            *(float4*)&smem[(r + i * 16) * 68 + c4] = v;
        }
        __syncthreads();
        int n = tid >> 4, k4 = (tid & 15) * 4;
        #pragma unroll
        for (int i = 0; i < 4; ++i) {
            int nn = n + i * 16;
            ushort4 hi;
            hi.x = f2bf(smem[(k4 + 0) * 68 + nn]);
            hi.y = f2bf(smem[(k4 + 1) * 68 + nn]);
            hi.z = f2bf(smem[(k4 + 2) * 68 + nn]);
            hi.w = f2bf(smem[(k4 + 3) * 68 + nn]);
            *(ushort4*)(Whi + (size_t)(n0 + nn) * K + k0 + k4) = hi;
        }
    } else if (bid < 5184) {               // ---- colsq
        int b2 = bid - 5120;
        int c = tid & 63, kq = tid >> 6;
        const float* W; int N, col, outoff;
        if (b2 < 48) { W = wa; N = N3C;  col = b2 * 64 + c;        outoff = 0;   }
        else         { W = wp; N = CDIM; col = (b2 - 48) * 64 + c; outoff = N3C; }
        float s = 0.f;
        int i0 = kq * 256;
        #pragma unroll 4
        for (int i = i0; i < i0 + 256; ++i) {
            float v = W[(size_t)i * N + col];
            s = fmaf(v, v, s);
        }
        smem[tid] = s;
        __syncthreads();
        if (kq == 0)
            ksq[outoff + col] = smem[c] + smem[64 + c] + smem[128 + c] + smem[192 + c];
    } else {                               // ---- rope table + osq zero
        int idx = (bid - 5184) * 256 + tid;   // [0, 65536)
        if (idx < BATCH * TSEQ) osq[idx] = 0.f;
        int t = idx >> 5, j = idx & 31;
        float inv = exp2f(-(float)j * 0.4152410118609203f);
        float ang = (float)t * inv;
        ropeSC[idx] = make_float2(cosf(ang), sinf(ang));
    }
}

// ---------------------------------------------------------------------------
// GEMM1: single-bf16 MFMA, yat epilogue + rotary table + bf16 pack.
// R7-proven config (47.4 us): 128x128 / 256-thread / 4-wave, double-buffered
// LDS with one __syncthreads per K-iter, XCD-chunked bijective swizzle
// (768 = 8 x 96, FETCH 38->29.5 MB). R8's counted-vmcnt/sched_barrier
// pipeline REGRESSED (92 us, VGPR 64->124, occupancy collapse) -- the
// m131/m141 lesson confirmed on this kernel: this structure is at its
// source-level plateau. Q scaled by (1/sqrt(D))*log2(e) for exp2 attn.
__global__ __launch_bounds__(256, 4) void gemm1_fused(
    const u16* __restrict__ Ah, const u16* __restrict__ Bh,
    const float* __restrict__ bias, const float* __restrict__ rowsq,
    const float* __restrict__ colsq, const float* __restrict__ alphap,
    const float2* __restrict__ ropeSC,
    u16* __restrict__ Qb, u16* __restrict__ Kb, u16* __restrict__ Vt) {
    constexpr int BK = 32;
    const int K = CDIM;
    __shared__ u16 Ash[2][128 * BK], Bsh[2][128 * BK];
    int tid = threadIdx.x;
    int lane = tid & 63, wv = tid >> 6;
    int quad = lane >> 4, l15 = lane & 15;
    int wr = wv >> 1, wc = wv & 1;

    // XCD-chunked swizzle: 768 blocks = 8 XCD x 96 (4 bm-bands x 24 bn).
    int lin = blockIdx.x + blockIdx.y * 24;
    int swz = (lin & 7) * 96 + (lin >> 3);
    int bn = (swz % 24) * 128;
    int bm = (swz / 24) * 128;

    int rsub = lane >> 2;
    int lc8 = (lane & 3) * 8;
    int gc8 = (((lane & 3) - (rsub >> 1)) & 3) * 8;
    int pf8 = ((quad + (l15 >> 1)) & 3) * 8;

    f32x4 acc[4][4];
    #pragma unroll
    for (int i = 0; i < 4; ++i)
        #pragma unroll
        for (int j = 0; j < 4; ++j) acc[i][j] = (f32x4){0.f, 0.f, 0.f, 0.f};

    auto STAGE = [&](int buf, int kt) {
        #pragma unroll
        for (int i = 0; i < 2; ++i) {
            int r = i * 64 + wv * 16 + rsub;
            gload16(Ah + (size_t)(bm + r) * K + kt + gc8, &Ash[buf][r * BK + lc8]);
            gload16(Bh + (size_t)(bn + r) * K + kt + gc8, &Bsh[buf][r * BK + lc8]);
        }
    };

    STAGE(0, 0);
    __syncthreads();                    // drains vmcnt(0): buf0 ready
    int cur = 0;

    for (int kt = 0; kt < K; kt += BK) {
        if (kt + BK < K) STAGE(cur ^ 1, kt + BK);
        bf16x8 fah[4], fbh[4];
        #pragma unroll
        for (int i = 0; i < 4; ++i)
            fah[i] = *(const bf16x8*)&Ash[cur][(wr * 64 + i * 16 + l15) * BK + pf8];
        #pragma unroll
        for (int j = 0; j < 4; ++j)
            fbh[j] = *(const bf16x8*)&Bsh[cur][(wc * 64 + j * 16 + l15) * BK + pf8];
        #pragma unroll
        for (int i = 0; i < 4; ++i)
            #pragma unroll
            for (int j = 0; j < 4; ++j)
                acc[i][j] = MFMA16(fah[i], fbh[j], acc[i][j]);
        __syncthreads();                // drains stage vmcnt + all ds_reads
        cur ^= 1;
    }

    float alpha = alphap[0];
    float scale = powf(sqrtf((float)N3C) / logf(1.0f + (float)N3C), alpha);
    int segc0 = bn + wc * 64;          // wave-uniform
    int seg = segc0 >> 10;             // 0=Q 1=K 2=V
    int h = (segc0 >> 6) & 15;
    int bglob = bm >> 11;
    int bh = bglob * NH + h;

    if (seg < 2) {
        u16* dst = (seg == 0) ? Qb : Kb;
        // Q: 1/sqrt(64) * log2(e) = 0.125 * 1.4426950408889634
        float qs = (seg == 0) ? 0.18033688011112043f : 1.0f;
        #pragma unroll
        for (int i = 0; i < 4; ++i) {
            int tb = bm + wr * 64 + i * 16 + quad * 4;
            #pragma unroll
            for (int r = 0; r < 4; ++r) {
                int row = tb + r;
                int t = row & (TSEQ - 1);
                float rs = rowsq[row];
                float y[4];
                #pragma unroll
                for (int j = 0; j < 4; ++j) {
                    int col = segc0 + j * 16 + l15;
                    float dot = acc[i][j][r];
                    float dist = rs + colsq[col] - 2.0f * dot + EPSY;
                    y[j] = dot * dot / dist * scale + bias[col];
                }
                float2 sc0 = ropeSC[t * 32 + l15];
                float2 sc1 = ropeSC[t * 32 + 16 + l15];
                float c0 = sc0.x, s0 = sc0.y, c1 = sc1.x, s1 = sc1.y;
                size_t ob = ((size_t)bh * TSEQ + t) * HD;
                dst[ob + l15]      = f2bf((y[0] * c0 - y[2] * s0) * qs);
                dst[ob + 16 + l15] = f2bf((y[1] * c1 - y[3] * s1) * qs);
                dst[ob + 32 + l15] = f2bf((y[2] * c0 + y[0] * s0) * qs);
                dst[ob + 48 + l15] = f2bf((y[3] * c1 + y[1] * s1) * qs);
            }
        }
    } else {
        #pragma unroll
        for (int i = 0; i < 4; ++i) {
            int tb = bm + wr * 64 + i * 16 + quad * 4;
            int t0 = tb & (TSEQ - 1);
            #pragma unroll
            for (int j = 0; j < 4; ++j) {
                int col = segc0 + j * 16 + l15;
                int d = j * 16 + l15;
                float cs = colsq[col], bi = bias[col];
                ushort4 pk;
                u16* pp = (u16*)&pk;
                #pragma unroll
                for (int r = 0; r < 4; ++r) {
                    float dot = acc[i][j][r];
                    float dist = rowsq[tb + r] + cs - 2.0f * dot + EPSY;
                    pp[r] = f2bf(dot * dot / dist * scale + bi);
                }
                *(ushort4*)(Vt + ((size_t)bh * HD + d) * TSEQ + t0) = pk;
            }
        }
    }
}

// ---------------------------------------------------------------------------
// GEMM2: single-bf16 MFMA + yat epilogue, fp32 out.
// THIS ROUND: 64x64 tile, 128-thread / 2-wave blocks -> grid (16,64) =
// 1024 blocks = 4 blocks/CU (was 512 = 2/CU, the worst latency-hiding in
// the pipeline). Intensity loss is L2-absorbed: entire B = 2 MB (fits one
// XCD's L2 after the 8x128 bijective swizzle), A-band refetch L2-served.
// Staging/read XOR pattern = the R6 gemm1 pattern (HW-correctness-proven).
__global__ __launch_bounds__(128, 4) void gemm_yat_mfma(
    const u16* __restrict__ Ah, const u16* __restrict__ Bh,
    const float* __restrict__ bias, const float* __restrict__ rowsq,
    const float* __restrict__ colsq, const float* __restrict__ alphap,
    float* __restrict__ outp, int M, int N, int K, float outf) {
    constexpr int BM = 64, BN = 64, BK = 32;
    __shared__ u16 Ash[2][BM * BK], Bsh[2][BN * BK];
    int tid = threadIdx.x;                    // [0,128)
    int lane = tid & 63, wv = tid >> 6;       // wv in {0,1}
    int quad = lane >> 4, l15 = lane & 15;

    // XCD-chunked swizzle: 1024 blocks = 8 XCD x 128 (8 bm-bands x 16 bn).
    int lin = blockIdx.x + blockIdx.y * 16;
    int swz = (lin & 7) * 128 + (lin >> 3);
    int bn = (swz & 15) * BN;
    int bm = (swz >> 4) * BM;

    // staging geometry: 128 threads cover 32 rows x 4 col-chunks per pass
    int rs = tid >> 2;                        // [0,32)
    int cc = tid & 3;
    int lc8 = cc * 8;
    int gc8 = ((cc - ((rs & 15) >> 1)) & 3) * 8;
    int pf8 = ((quad + (l15 >> 1)) & 3) * 8;

    f32x4 acc[2][4];
    #pragma unroll
    for (int i = 0; i < 2; ++i)
        #pragma unroll
        for (int j = 0; j < 4; ++j) acc[i][j] = (f32x4){0.f, 0.f, 0.f, 0.f};

    auto STAGE = [&](int buf, int kt) {
        #pragma unroll
        for (int p = 0; p < 2; ++p) {         // A: 64 rows, B: 64 rows
            int r = p * 32 + rs;
            gload16(Ah + (size_t)(bm + r) * K + kt + gc8, &Ash[buf][r * BK + lc8]);
            gload16(Bh + (size_t)(bn + r) * K + kt + gc8, &Bsh[buf][r * BK + lc8]);
        }
    };

    STAGE(0, 0);
    __syncthreads();                    // buf0 ready
    int cur = 0;

    for (int kt = 0; kt < K; kt += BK) {
        if (kt + BK < K) STAGE(cur ^ 1, kt + BK);
        bf16x8 fah[2], fbh[4];
        #pragma unroll
        for (int i = 0; i < 2; ++i)
            fah[i] = *(const bf16x8*)&Ash[cur][(wv * 32 + i * 16 + l15) * BK + pf8];
        #pragma unroll
        for (int j = 0; j < 4; ++j)
            fbh[j] = *(const bf16x8*)&Bsh[cur][(j * 16 + l15) * BK + pf8];
        #pragma unroll
        for (int i = 0; i < 2; ++i)
            #pragma unroll
            for (int j = 0; j < 4; ++j)
                acc[i][j] = MFMA16(fah[i], fbh[j], acc[i][j]);
        __syncthreads();
        cur ^= 1;
    }

    float alpha = alphap[0];
    float scale = powf(sqrtf(outf) / logf(1.0f + outf), alpha);
    #pragma unroll
    for (int j = 0; j < 4; ++j) {
        int col = bn + j * 16 + l15;
        float cs = colsq[col], bi = bias[col];
        #pragma unroll
        for (int i = 0; i < 2; ++i) {
            #pragma unroll
            for (int r = 0; r < 4; ++r) {
                int row = bm + wv * 32 + i * 16 + quad * 4 + r;
                float dot = acc[i][j][r];
                float dist = rowsq[row] + cs - 2.0f * dot + EPSY;
                outp[(size_t)row * N + col] = dot * dot / dist * scale + bi;
            }
        }
    }
}

// ---------------------------------------------------------------------------
// S^T bf16 MFMA causal flash attention, fixed-shift softmax, exp2 domain
// (log2e folded into Q scale in gemm1). 512-thread blocks (8 waves, 128
// queries) sharing one K/V staging; waves with fully-masked tiles skip
// compute wave-uniformly but keep barriers. P-redistribution:
// v_permlane32_swap + ds_swizzle. Double-buffered K/V, one barrier/iter,
// setprio kept. grid (32 bh, 16 qblk) = 512 blocks, all co-resident.
__global__ __launch_bounds__(512) void attn_mfma(
    const u16* __restrict__ Qb, const u16* __restrict__ Kb,
    const u16* __restrict__ Vt, u16* __restrict__ Chi,
    float* __restrict__ osq) {
    __shared__ u16 Ksh[2][64 * 64];   // [buf][key][d-chunks, rotated by key]
    __shared__ u16 Vsh[2][64 * 64];   // [buf][d][key-chunks, rotated by d]
    int tid = threadIdx.x;
    int lane = tid & 63, wv = tid >> 6;       // wv in {0..7}
    int quad = lane >> 4, l15 = lane & 15;
    const bool oddq = (quad & 1) != 0;
    int bh = blockIdx.x;
    int b = bh >> 4, h = bh & 15;
    const u16* Qh = Qb + (size_t)bh * TSEQ * HD;
    const u16* Kh = Kb + (size_t)bh * TSEQ * HD;
    const u16* Vh = Vt + (size_t)bh * HD * TSEQ;
    const f32x4 zf = {0.f, 0.f, 0.f, 0.f};

    int qbb = 15 - blockIdx.y;         // longest first; 128-query block
    int qw = qbb * 128 + wv * 16;      // this wave's 16 queries
    int NT = 2 * qbb + 2;              // k-tiles this block needs
    bf16x8 bq0 = *(const bf16x8*)(Qh + (size_t)(qw + l15) * HD + quad * 8);
    bf16x8 bq1 = *(const bf16x8*)(Qh + (size_t)(qw + l15) * HD + 32 + quad * 8);

    f32x4 o[4] = {zf, zf, zf, zf};
    float l = 0.f;

    auto STAGE = [&](int buf, int kt) {
        int k0s = kt * 64;
        int rowi = tid >> 3, ch = tid & 7;    // 512 threads cover 64x8 chunks
        int gk = (ch + rowi) & 7;
        gload16(Kh + (size_t)(k0s + rowi) * HD + gk * 8, &Ksh[buf][tid * 8]);
        gload16(Vh + (size_t)rowi * TSEQ + k0s + gk * 8, &Vsh[buf][tid * 8]);
    };

    STAGE(0, 0);
    __syncthreads();                   // drains vmcnt(0): buf0 ready
    int cur = 0;

    for (int kt = 0; kt < NT; ++kt) {
        int k0 = kt * 64;
        if (kt + 1 < NT) STAGE(cur ^ 1, kt + 1);
        if (k0 <= qw + 15) {           // wave-uniform: skip fully-masked tiles
            const u16* Kc = Ksh[cur];
            const u16* Vc = Vsh[cur];

            f32x4 st[4];
            __builtin_amdgcn_s_setprio(1);
            #pragma unroll
            for (int mt = 0; mt < 4; ++mt) {
                int key = mt * 16 + l15;
                bf16x8 a0 = *(const bf16x8*)&Kc[key * 64 + ((quad - key) & 7) * 8];
                bf16x8 a1 = *(const bf16x8*)&Kc[key * 64 + ((4 + quad - key) & 7) * 8];
                st[mt] = MFMA16(a0, bq0, zf);
                st[mt] = MFMA16(a1, bq1, st[mt]);
            }
            __builtin_amdgcn_s_setprio(0);
            if (k0 + 63 > qw) {        // diagonal tile for this wave
                int q = qw + l15;
                #pragma unroll
                for (int mt = 0; mt < 4; ++mt)
                    #pragma unroll
                    for (int r = 0; r < 4; ++r)
                        if (k0 + mt * 16 + quad * 4 + r > q) st[mt][r] = -1e30f;
            }
            u32 pp[4][2];
            #pragma unroll
            for (int mt = 0; mt < 4; ++mt) {
                float p0 = __builtin_amdgcn_exp2f(st[mt][0]);
                float p1 = __builtin_amdgcn_exp2f(st[mt][1]);
                float p2 = __builtin_amdgcn_exp2f(st[mt][2]);
                float p3 = __builtin_amdgcn_exp2f(st[mt][3]);
                l += (p0 + p1) + (p2 + p3);
                pp[mt][0] = cvtpk_bf16(p0, p1);
                pp[mt][1] = cvtpk_bf16(p2, p3);
            }
            // PV: redistribute P across quads (same l15) with
            // permlane32_swap (cross-half) + ds_swizzle xor-16 (within-half).
            #pragma unroll
            for (int s = 0; s < 2; ++s) {
                u32x2 r0 = __builtin_amdgcn_permlane32_swap(
                    pp[2 * s][0], pp[2 * s + 1][0], false, false);
                u32 sA0 = (u32)__builtin_amdgcn_ds_swizzle((int)r0.x, 0x401F);
                u32 sB0 = (u32)__builtin_amdgcn_ds_swizzle((int)r0.y, 0x401F);
                u32x2 r1 = __builtin_amdgcn_permlane32_swap(
                    pp[2 * s][1], pp[2 * s + 1][1], false, false);
                u32 sA1 = (u32)__builtin_amdgcn_ds_swizzle((int)r1.x, 0x401F);
                u32 sB1 = (u32)__builtin_amdgcn_ds_swizzle((int)r1.y, 0x401F);
                u32 bw0 = oddq ? sB0 : r0.x;
                u32 bw1 = oddq ? sB1 : r1.x;
                u32 bw2 = oddq ? r0.y : sA0;
                u32 bw3 = oddq ? r1.y : sA1;
                bf16x8 bfr;
                *(u32*)&((short*)&bfr)[0] = bw0;
                *(u32*)&((short*)&bfr)[2] = bw1;
                *(u32*)&((short*)&bfr)[4] = bw2;
                *(u32*)&((short*)&bfr)[6] = bw3;
                __builtin_amdgcn_s_setprio(1);
                #pragma unroll
                for (int dt = 0; dt < 4; ++dt) {
                    int d = dt * 16 + l15;
                    bf16x8 av = *(const bf16x8*)&Vc[d * 64 + ((s * 4 + quad - d) & 7) * 8];
                    o[dt] = MFMA16(av, bfr, o[dt]);
                }
                __builtin_amdgcn_s_setprio(0);
            }
        }
        __syncthreads();               // drains stage vmcnt; all waves done
        cur ^= 1;
    }

    // deferred cross-quad l reduction, bf16 write, fused row-sumsq
    l += __shfl_xor(l, 16, 64);
    l += __shfl_xor(l, 32, 64);
    float inv = 1.0f / l;
    int row = (b << 11) + qw + l15;
    float ss = 0.f;
    #pragma unroll
    for (int dt = 0; dt < 4; ++dt) {
        float v0 = o[dt][0] * inv, v1 = o[dt][1] * inv;
        float v2 = o[dt][2] * inv, v3 = o[dt][3] * inv;
        ss += v0 * v0 + v1 * v1 + v2 * v2 + v3 * v3;
        uint2 pk2;
        pk2.x = cvtpk_bf16(v0, v1);
        pk2.y = cvtpk_bf16(v2, v3);
        *(uint2*)(Chi + (size_t)row * CDIM + h * HD + dt * 16 + quad * 4) = pk2;
    }
    ss += __shfl_xor(ss, 16, 64);
    ss += __shfl_xor(ss, 32, 64);
    if (quad == 0) atomicAdd(osq + row, ss);
}

// ---------------------------------------------------------------------------
extern "C" void kernel_launch(void* const* d_in, const int* in_sizes, int n_in,
                              void* d_out, int out_size, void* d_ws, size_t ws_size,
                              hipStream_t stream) {
    const float* x      = (const float*)d_in[0];
    const float* w_attn = (const float*)d_in[2];
    const float* b_attn = (const float*)d_in[3];
    const float* a_attn = (const float*)d_in[4];
    const float* w_proj = (const float*)d_in[5];
    const float* b_proj = (const float*)d_in[6];
    const float* a_proj = (const float*)d_in[7];
    float* outp = (float*)d_out;

    char* ws = (char*)d_ws;
    float* ksq = (float*)(ws);
    float* xsq = (float*)(ws + 16384);
    float* osq = (float*)(ws + 32768);
    char* pA  = ws + 65536;                    // 16.78 MB: Ahi -> Chi
    u16* Ahi = (u16*)pA;
    u16* Chi = (u16*)pA;                       // alias (Ahi dead after GEMM1)
    char* pWt = pA + 16777216;                 // 6.29 MB
    u16* Wthi = (u16*)pWt;
    char* pWp = pWt + 6291456;                 // 2.10 MB
    u16* Wphi = (u16*)pWp;
    char* pQ = pWp + 2097152;                  // 25.17 MB: Qb,Kb,Vt
    u16* Qb = (u16*)pQ;
    u16* Kb = (u16*)(pQ + 8388608);
    u16* Vt = (u16*)(pQ + 16777216);
    float2* ropeSC = (float2*)(pQ + 25165824); // 512 KB

    prep_kernel<<<5440, 256, 0, stream>>>(
        x, w_attn, w_proj, Ahi, Wthi, Wphi, ksq, xsq, osq, ropeSC);
    gemm1_fused<<<dim3(N3C / 128, (BATCH * TSEQ) / 128), 256, 0, stream>>>(
        Ahi, Wthi, b_attn, xsq, ksq, a_attn, ropeSC, Qb, Kb, Vt);
    attn_mfma<<<dim3(BATCH * NH, 16), 512, 0, stream>>>(Qb, Kb, Vt, Chi, osq);
    gemm_yat_mfma<<<dim3(CDIM / 64, (BATCH * TSEQ) / 64), 128, 0, stream>>>(
        Chi, Wphi, b_proj, osq, ksq + N3C, a_proj, outp,
        BATCH * TSEQ, CDIM, CDIM, (float)CDIM);
}

// Round 10
// 217.824 us; speedup vs baseline: 1.1044x; 1.0230x over previous
//
#include <hip/hip_runtime.h>
#include <math.h>

#define TSEQ  2048
#define BATCH 2
#define NH    16
#define HD    64
#define CDIM  1024
#define N3C   3072
#define EPSY  1e-6f

typedef unsigned short u16;
typedef unsigned int u32;
typedef __attribute__((ext_vector_type(2))) unsigned int u32x2;
typedef __attribute__((ext_vector_type(8))) short bf16x8;
typedef __attribute__((ext_vector_type(4))) float f32x4;

#define MFMA16(a, b, c) __builtin_amdgcn_mfma_f32_16x16x32_bf16(a, b, c, 0, 0, 0)

__device__ __forceinline__ u16 f2bf(float f) {
    unsigned u = __float_as_uint(f);
    return (u16)((u + 0x7fffu + ((u >> 16) & 1u)) >> 16);
}
// packed f32x2 -> bf16x2 (RNE, identical to f2bf) in ONE VALU instruction
__device__ __forceinline__ u32 cvtpk_bf16(float lo, float hi) {
    u32 r;
    asm("v_cvt_pk_bf16_f32 %0, %1, %2" : "=v"(r) : "v"(lo), "v"(hi));
    return r;
}
__device__ __forceinline__ void gload16(const void* g, void* l) {
    __builtin_amdgcn_global_load_lds(
        (const __attribute__((address_space(1))) unsigned int*)g,
        (__attribute__((address_space(3))) unsigned int*)l, 16, 0, 0);
}

// ---------------------------------------------------------------------------
// Fused prep: one launch replaces rope_init/colsq/convert_rows/convert_wT x2.
__global__ __launch_bounds__(256) void prep_kernel(
    const float* __restrict__ x, const float* __restrict__ wa,
    const float* __restrict__ wp, u16* __restrict__ Ahi,
    u16* __restrict__ Wthi, u16* __restrict__ Wphi,
    float* __restrict__ ksq, float* __restrict__ xsq,
    float* __restrict__ osq, float2* __restrict__ ropeSC) {
    __shared__ float smem[64 * 68];
    int bid = blockIdx.x, tid = threadIdx.x;

    if (bid < 4096) {                      // ---- convert_rows
        int lane = tid & 63, wv = tid >> 6;
        size_t base = (size_t)bid * CDIM + tid * 4;
        float4 v = *(const float4*)(x + base);
        ushort4 hi;
        hi.x = f2bf(v.x); hi.y = f2bf(v.y); hi.z = f2bf(v.z); hi.w = f2bf(v.w);
        *(ushort4*)(Ahi + base) = hi;
        float s = v.x * v.x + v.y * v.y + v.z * v.z + v.w * v.w;
        #pragma unroll
        for (int off = 32; off; off >>= 1) s += __shfl_down(s, off, 64);
        if (lane == 0) smem[wv] = s;
        __syncthreads();
        if (tid == 0) xsq[bid] = smem[0] + smem[1] + smem[2] + smem[3];
    } else if (bid < 5120) {               // ---- transpose+convert weights
        const float* W; u16* Whi; int K, N, bx, by;
        if (bid < 4864) {
            int t = bid - 4096; W = wa; Whi = Wthi; K = CDIM; N = N3C;
            bx = t % 48; by = t / 48;
        } else {
            int t = bid - 4864; W = wp; Whi = Wphi; K = CDIM; N = CDIM;
            bx = t % 16; by = t / 16;
        }
        int k0 = by * 64, n0 = bx * 64;
        int r = tid >> 4, c4 = (tid & 15) * 4;
        #pragma unroll
        for (int i = 0; i < 4; ++i) {
            int k = k0 + r + i * 16;
            float4 v = *(const float4*)(W + (size_t)k * N + n0 + c4);
            *(float4*)&smem[(r + i * 16) * 68 + c4] = v;
        }
        __syncthreads();
        int n = tid >> 4, k4 = (tid & 15) * 4;
        #pragma unroll
        for (int i = 0; i < 4; ++i) {
            int nn = n + i * 16;
            ushort4 hi;
            hi.x = f2bf(smem[(k4 + 0) * 68 + nn]);
            hi.y = f2bf(smem[(k4 + 1) * 68 + nn]);
            hi.z = f2bf(smem[(k4 + 2) * 68 + nn]);
            hi.w = f2bf(smem[(k4 + 3) * 68 + nn]);
            *(ushort4*)(Whi + (size_t)(n0 + nn) * K + k0 + k4) = hi;
        }
    } else if (bid < 5184) {               // ---- colsq
        int b2 = bid - 5120;
        int c = tid & 63, kq = tid >> 6;
        const float* W; int N, col, outoff;
        if (b2 < 48) { W = wa; N = N3C;  col = b2 * 64 + c;        outoff = 0;   }
        else         { W = wp; N = CDIM; col = (b2 - 48) * 64 + c; outoff = N3C; }
        float s = 0.f;
        int i0 = kq * 256;
        #pragma unroll 4
        for (int i = i0; i < i0 + 256; ++i) {
            float v = W[(size_t)i * N + col];
            s = fmaf(v, v, s);
        }
        smem[tid] = s;
        __syncthreads();
        if (kq == 0)
            ksq[outoff + col] = smem[c] + smem[64 + c] + smem[128 + c] + smem[192 + c];
    } else {                               // ---- rope table + osq zero
        int idx = (bid - 5184) * 256 + tid;   // [0, 65536)
        if (idx < BATCH * TSEQ) osq[idx] = 0.f;
        int t = idx >> 5, j = idx & 31;
        float inv = exp2f(-(float)j * 0.4152410118609203f);
        float ang = (float)t * inv;
        ropeSC[idx] = make_float2(cosf(ang), sinf(ang));
    }
}

// ---------------------------------------------------------------------------
// GEMM1: single-bf16 MFMA, yat epilogue + rotary table + bf16 pack.
// R7-proven config (47.4 us): 128x128 / 256-thread / 4-wave, double-buffered
// LDS with one __syncthreads per K-iter, XCD-chunked bijective swizzle
// (768 = 8 x 96, FETCH 38->29.5 MB). R8's counted-vmcnt/sched_barrier
// pipeline REGRESSED (92 us) -- m131/m141 confirmed: source-level plateau.
// Q scaled by (1/sqrt(D))*log2(e) for exp2-domain attn.
__global__ __launch_bounds__(256, 4) void gemm1_fused(
    const u16* __restrict__ Ah, const u16* __restrict__ Bh,
    const float* __restrict__ bias, const float* __restrict__ rowsq,
    const float* __restrict__ colsq, const float* __restrict__ alphap,
    const float2* __restrict__ ropeSC,
    u16* __restrict__ Qb, u16* __restrict__ Kb, u16* __restrict__ Vt) {
    constexpr int BK = 32;
    const int K = CDIM;
    __shared__ u16 Ash[2][128 * BK], Bsh[2][128 * BK];
    int tid = threadIdx.x;
    int lane = tid & 63, wv = tid >> 6;
    int quad = lane >> 4, l15 = lane & 15;
    int wr = wv >> 1, wc = wv & 1;

    // XCD-chunked swizzle: 768 blocks = 8 XCD x 96 (4 bm-bands x 24 bn).
    int lin = blockIdx.x + blockIdx.y * 24;
    int swz = (lin & 7) * 96 + (lin >> 3);
    int bn = (swz % 24) * 128;
    int bm = (swz / 24) * 128;

    int rsub = lane >> 2;
    int lc8 = (lane & 3) * 8;
    int gc8 = (((lane & 3) - (rsub >> 1)) & 3) * 8;
    int pf8 = ((quad + (l15 >> 1)) & 3) * 8;

    f32x4 acc[4][4];
    #pragma unroll
    for (int i = 0; i < 4; ++i)
        #pragma unroll
        for (int j = 0; j < 4; ++j) acc[i][j] = (f32x4){0.f, 0.f, 0.f, 0.f};

    auto STAGE = [&](int buf, int kt) {
        #pragma unroll
        for (int i = 0; i < 2; ++i) {
            int r = i * 64 + wv * 16 + rsub;
            gload16(Ah + (size_t)(bm + r) * K + kt + gc8, &Ash[buf][r * BK + lc8]);
            gload16(Bh + (size_t)(bn + r) * K + kt + gc8, &Bsh[buf][r * BK + lc8]);
        }
    };

    STAGE(0, 0);
    __syncthreads();                    // drains vmcnt(0): buf0 ready
    int cur = 0;

    for (int kt = 0; kt < K; kt += BK) {
        if (kt + BK < K) STAGE(cur ^ 1, kt + BK);
        bf16x8 fah[4], fbh[4];
        #pragma unroll
        for (int i = 0; i < 4; ++i)
            fah[i] = *(const bf16x8*)&Ash[cur][(wr * 64 + i * 16 + l15) * BK + pf8];
        #pragma unroll
        for (int j = 0; j < 4; ++j)
            fbh[j] = *(const bf16x8*)&Bsh[cur][(wc * 64 + j * 16 + l15) * BK + pf8];
        #pragma unroll
        for (int i = 0; i < 4; ++i)
            #pragma unroll
            for (int j = 0; j < 4; ++j)
                acc[i][j] = MFMA16(fah[i], fbh[j], acc[i][j]);
        __syncthreads();                // drains stage vmcnt + all ds_reads
        cur ^= 1;
    }

    float alpha = alphap[0];
    float scale = powf(sqrtf((float)N3C) / logf(1.0f + (float)N3C), alpha);
    int segc0 = bn + wc * 64;          // wave-uniform
    int seg = segc0 >> 10;             // 0=Q 1=K 2=V
    int h = (segc0 >> 6) & 15;
    int bglob = bm >> 11;
    int bh = bglob * NH + h;

    if (seg < 2) {
        u16* dst = (seg == 0) ? Qb : Kb;
        // Q: 1/sqrt(64) * log2(e) = 0.125 * 1.4426950408889634
        float qs = (seg == 0) ? 0.18033688011112043f : 1.0f;
        #pragma unroll
        for (int i = 0; i < 4; ++i) {
            int tb = bm + wr * 64 + i * 16 + quad * 4;
            #pragma unroll
            for (int r = 0; r < 4; ++r) {
                int row = tb + r;
                int t = row & (TSEQ - 1);
                float rs = rowsq[row];
                float y[4];
                #pragma unroll
                for (int j = 0; j < 4; ++j) {
                    int col = segc0 + j * 16 + l15;
                    float dot = acc[i][j][r];
                    float dist = rs + colsq[col] - 2.0f * dot + EPSY;
                    y[j] = dot * dot / dist * scale + bias[col];
                }
                float2 sc0 = ropeSC[t * 32 + l15];
                float2 sc1 = ropeSC[t * 32 + 16 + l15];
                float c0 = sc0.x, s0 = sc0.y, c1 = sc1.x, s1 = sc1.y;
                size_t ob = ((size_t)bh * TSEQ + t) * HD;
                dst[ob + l15]      = f2bf((y[0] * c0 - y[2] * s0) * qs);
                dst[ob + 16 + l15] = f2bf((y[1] * c1 - y[3] * s1) * qs);
                dst[ob + 32 + l15] = f2bf((y[2] * c0 + y[0] * s0) * qs);
                dst[ob + 48 + l15] = f2bf((y[3] * c1 + y[1] * s1) * qs);
            }
        }
    } else {
        #pragma unroll
        for (int i = 0; i < 4; ++i) {
            int tb = bm + wr * 64 + i * 16 + quad * 4;
            int t0 = tb & (TSEQ - 1);
            #pragma unroll
            for (int j = 0; j < 4; ++j) {
                int col = segc0 + j * 16 + l15;
                int d = j * 16 + l15;
                float cs = colsq[col], bi = bias[col];
                ushort4 pk;
                u16* pp = (u16*)&pk;
                #pragma unroll
                for (int r = 0; r < 4; ++r) {
                    float dot = acc[i][j][r];
                    float dist = rowsq[tb + r] + cs - 2.0f * dot + EPSY;
                    pp[r] = f2bf(dot * dot / dist * scale + bi);
                }
                *(ushort4*)(Vt + ((size_t)bh * HD + d) * TSEQ + t0) = pk;
            }
        }
    }
}

// ---------------------------------------------------------------------------
// GEMM2: single-bf16 MFMA + yat epilogue, fp32 out. 64x64 tile, 128-thread
// / 2-wave blocks, grid 1024 = 4 blocks/CU, XCD-chunked swizzle (8 x 128).
// R9: -2.2 us total vs 128x64.
__global__ __launch_bounds__(128, 4) void gemm_yat_mfma(
    const u16* __restrict__ Ah, const u16* __restrict__ Bh,
    const float* __restrict__ bias, const float* __restrict__ rowsq,
    const float* __restrict__ colsq, const float* __restrict__ alphap,
    float* __restrict__ outp, int M, int N, int K, float outf) {
    constexpr int BM = 64, BN = 64, BK = 32;
    __shared__ u16 Ash[2][BM * BK], Bsh[2][BN * BK];
    int tid = threadIdx.x;                    // [0,128)
    int lane = tid & 63, wv = tid >> 6;       // wv in {0,1}
    int quad = lane >> 4, l15 = lane & 15;

    // XCD-chunked swizzle: 1024 blocks = 8 XCD x 128 (8 bm-bands x 16 bn).
    int lin = blockIdx.x + blockIdx.y * 16;
    int swz = (lin & 7) * 128 + (lin >> 3);
    int bn = (swz & 15) * BN;
    int bm = (swz >> 4) * BM;

    // staging geometry: 128 threads cover 32 rows x 4 col-chunks per pass
    int rs = tid >> 2;                        // [0,32)
    int cc = tid & 3;
    int lc8 = cc * 8;
    int gc8 = ((cc - ((rs & 15) >> 1)) & 3) * 8;
    int pf8 = ((quad + (l15 >> 1)) & 3) * 8;

    f32x4 acc[2][4];
    #pragma unroll
    for (int i = 0; i < 2; ++i)
        #pragma unroll
        for (int j = 0; j < 4; ++j) acc[i][j] = (f32x4){0.f, 0.f, 0.f, 0.f};

    auto STAGE = [&](int buf, int kt) {
        #pragma unroll
        for (int p = 0; p < 2; ++p) {         // A: 64 rows, B: 64 rows
            int r = p * 32 + rs;
            gload16(Ah + (size_t)(bm + r) * K + kt + gc8, &Ash[buf][r * BK + lc8]);
            gload16(Bh + (size_t)(bn + r) * K + kt + gc8, &Bsh[buf][r * BK + lc8]);
        }
    };

    STAGE(0, 0);
    __syncthreads();                    // buf0 ready
    int cur = 0;

    for (int kt = 0; kt < K; kt += BK) {
        if (kt + BK < K) STAGE(cur ^ 1, kt + BK);
        bf16x8 fah[2], fbh[4];
        #pragma unroll
        for (int i = 0; i < 2; ++i)
            fah[i] = *(const bf16x8*)&Ash[cur][(wv * 32 + i * 16 + l15) * BK + pf8];
        #pragma unroll
        for (int j = 0; j < 4; ++j)
            fbh[j] = *(const bf16x8*)&Bsh[cur][(j * 16 + l15) * BK + pf8];
        #pragma unroll
        for (int i = 0; i < 2; ++i)
            #pragma unroll
            for (int j = 0; j < 4; ++j)
                acc[i][j] = MFMA16(fah[i], fbh[j], acc[i][j]);
        __syncthreads();
        cur ^= 1;
    }

    float alpha = alphap[0];
    float scale = powf(sqrtf(outf) / logf(1.0f + outf), alpha);
    #pragma unroll
    for (int j = 0; j < 4; ++j) {
        int col = bn + j * 16 + l15;
        float cs = colsq[col], bi = bias[col];
        #pragma unroll
        for (int i = 0; i < 2; ++i) {
            #pragma unroll
            for (int r = 0; r < 4; ++r) {
                int row = bm + wv * 32 + i * 16 + quad * 4 + r;
                float dot = acc[i][j][r];
                float dist = rowsq[row] + cs - 2.0f * dot + EPSY;
                outp[(size_t)row * N + col] = dot * dot / dist * scale + bi;
            }
        }
    }
}

// ---------------------------------------------------------------------------
// S^T bf16 MFMA causal flash attention, fixed-shift softmax, exp2 domain.
// THIS ROUND (KVBLK=128 pairing): stage a PAIR of 64-key tiles per buffer,
// compute both sub-tiles back-to-back, ONE barrier per pair -- halves the
// per-barrier fixed cost (drain + barrier + sched gap, ~half of each
// 3000-cyc iteration) against 2x the work. NT = 2*qbb+2 is always even so
// pairing is exact. LDS 32->64 KB: grid is 2 blocks/CU and 64 KB still
// allows 2 blocks/CU -> zero occupancy cost. Per-sub-tile compute,
// masking, skip logic byte-identical. 512-thread blocks (8 waves, 128
// queries), v_permlane32_swap + ds_swizzle P-redistribution, setprio.
__global__ __launch_bounds__(512) void attn_mfma(
    const u16* __restrict__ Qb, const u16* __restrict__ Kb,
    const u16* __restrict__ Vt, u16* __restrict__ Chi,
    float* __restrict__ osq) {
    __shared__ u16 Ksh[2][2][64 * 64];   // [buf][sub][key][d-chunks, rotated]
    __shared__ u16 Vsh[2][2][64 * 64];   // [buf][sub][d][key-chunks, rotated]
    int tid = threadIdx.x;
    int lane = tid & 63, wv = tid >> 6;       // wv in {0..7}
    int quad = lane >> 4, l15 = lane & 15;
    const bool oddq = (quad & 1) != 0;
    int bh = blockIdx.x;
    int b = bh >> 4, h = bh & 15;
    const u16* Qh = Qb + (size_t)bh * TSEQ * HD;
    const u16* Kh = Kb + (size_t)bh * TSEQ * HD;
    const u16* Vh = Vt + (size_t)bh * HD * TSEQ;
    const f32x4 zf = {0.f, 0.f, 0.f, 0.f};

    int qbb = 15 - blockIdx.y;         // longest first; 128-query block
    int qw = qbb * 128 + wv * 16;      // this wave's 16 queries
    int NP = qbb + 1;                  // pairs of k-tiles this block needs
    bf16x8 bq0 = *(const bf16x8*)(Qh + (size_t)(qw + l15) * HD + quad * 8);
    bf16x8 bq1 = *(const bf16x8*)(Qh + (size_t)(qw + l15) * HD + 32 + quad * 8);

    f32x4 o[4] = {zf, zf, zf, zf};
    float l = 0.f;

    auto STAGE = [&](int buf, int pt) {
        int rowi = tid >> 3, ch = tid & 7;    // 512 threads cover 64x8 chunks
        int gk = (ch + rowi) & 7;
        #pragma unroll
        for (int s2 = 0; s2 < 2; ++s2) {
            int k0s = (pt * 2 + s2) * 64;
            gload16(Kh + (size_t)(k0s + rowi) * HD + gk * 8, &Ksh[buf][s2][tid * 8]);
            gload16(Vh + (size_t)rowi * TSEQ + k0s + gk * 8, &Vsh[buf][s2][tid * 8]);
        }
    };

    STAGE(0, 0);
    __syncthreads();                   // drains vmcnt(0): buf0 (pair 0) ready
    int cur = 0;

    for (int pt = 0; pt < NP; ++pt) {
        if (pt + 1 < NP) STAGE(cur ^ 1, pt + 1);
        #pragma unroll
        for (int s2 = 0; s2 < 2; ++s2) {
            int k0 = (pt * 2 + s2) * 64;
            if (k0 > qw + 15) continue;    // wave-uniform: fully-masked tile
            const u16* Kc = Ksh[cur][s2];
            const u16* Vc = Vsh[cur][s2];

            f32x4 st[4];
            __builtin_amdgcn_s_setprio(1);
            #pragma unroll
            for (int mt = 0; mt < 4; ++mt) {
                int key = mt * 16 + l15;
                bf16x8 a0 = *(const bf16x8*)&Kc[key * 64 + ((quad - key) & 7) * 8];
                bf16x8 a1 = *(const bf16x8*)&Kc[key * 64 + ((4 + quad - key) & 7) * 8];
                st[mt] = MFMA16(a0, bq0, zf);
                st[mt] = MFMA16(a1, bq1, st[mt]);
            }
            __builtin_amdgcn_s_setprio(0);
            if (k0 + 63 > qw) {        // diagonal tile for this wave
                int q = qw + l15;
                #pragma unroll
                for (int mt = 0; mt < 4; ++mt)
                    #pragma unroll
                    for (int r = 0; r < 4; ++r)
                        if (k0 + mt * 16 + quad * 4 + r > q) st[mt][r] = -1e30f;
            }
            u32 pp[4][2];
            #pragma unroll
            for (int mt = 0; mt < 4; ++mt) {
                float p0 = __builtin_amdgcn_exp2f(st[mt][0]);
                float p1 = __builtin_amdgcn_exp2f(st[mt][1]);
                float p2 = __builtin_amdgcn_exp2f(st[mt][2]);
                float p3 = __builtin_amdgcn_exp2f(st[mt][3]);
                l += (p0 + p1) + (p2 + p3);
                pp[mt][0] = cvtpk_bf16(p0, p1);
                pp[mt][1] = cvtpk_bf16(p2, p3);
            }
            // PV: redistribute P across quads (same l15) with
            // permlane32_swap (cross-half) + ds_swizzle xor-16 (within-half).
            #pragma unroll
            for (int s = 0; s < 2; ++s) {
                u32x2 r0 = __builtin_amdgcn_permlane32_swap(
                    pp[2 * s][0], pp[2 * s + 1][0], false, false);
                u32 sA0 = (u32)__builtin_amdgcn_ds_swizzle((int)r0.x, 0x401F);
                u32 sB0 = (u32)__builtin_amdgcn_ds_swizzle((int)r0.y, 0x401F);
                u32x2 r1 = __builtin_amdgcn_permlane32_swap(
                    pp[2 * s][1], pp[2 * s + 1][1], false, false);
                u32 sA1 = (u32)__builtin_amdgcn_ds_swizzle((int)r1.x, 0x401F);
                u32 sB1 = (u32)__builtin_amdgcn_ds_swizzle((int)r1.y, 0x401F);
                u32 bw0 = oddq ? sB0 : r0.x;
                u32 bw1 = oddq ? sB1 : r1.x;
                u32 bw2 = oddq ? r0.y : sA0;
                u32 bw3 = oddq ? r1.y : sA1;
                bf16x8 bfr;
                *(u32*)&((short*)&bfr)[0] = bw0;
                *(u32*)&((short*)&bfr)[2] = bw1;
                *(u32*)&((short*)&bfr)[4] = bw2;
                *(u32*)&((short*)&bfr)[6] = bw3;
                __builtin_amdgcn_s_setprio(1);
                #pragma unroll
                for (int dt = 0; dt < 4; ++dt) {
                    int d = dt * 16 + l15;
                    bf16x8 av = *(const bf16x8*)&Vc[d * 64 + ((s * 4 + quad - d) & 7) * 8];
                    o[dt] = MFMA16(av, bfr, o[dt]);
                }
                __builtin_amdgcn_s_setprio(0);
            }
        }
        __syncthreads();               // drains stage vmcnt; all waves done
        cur ^= 1;
    }

    // deferred cross-quad l reduction, bf16 write, fused row-sumsq
    l += __shfl_xor(l, 16, 64);
    l += __shfl_xor(l, 32, 64);
    float inv = 1.0f / l;
    int row = (b << 11) + qw + l15;
    float ss = 0.f;
    #pragma unroll
    for (int dt = 0; dt < 4; ++dt) {
        float v0 = o[dt][0] * inv, v1 = o[dt][1] * inv;
        float v2 = o[dt][2] * inv, v3 = o[dt][3] * inv;
        ss += v0 * v0 + v1 * v1 + v2 * v2 + v3 * v3;
        uint2 pk2;
        pk2.x = cvtpk_bf16(v0, v1);
        pk2.y = cvtpk_bf16(v2, v3);
        *(uint2*)(Chi + (size_t)row * CDIM + h * HD + dt * 16 + quad * 4) = pk2;
    }
    ss += __shfl_xor(ss, 16, 64);
    ss += __shfl_xor(ss, 32, 64);
    if (quad == 0) atomicAdd(osq + row, ss);
}

// ---------------------------------------------------------------------------
extern "C" void kernel_launch(void* const* d_in, const int* in_sizes, int n_in,
                              void* d_out, int out_size, void* d_ws, size_t ws_size,
                              hipStream_t stream) {
    const float* x      = (const float*)d_in[0];
    const float* w_attn = (const float*)d_in[2];
    const float* b_attn = (const float*)d_in[3];
    const float* a_attn = (const float*)d_in[4];
    const float* w_proj = (const float*)d_in[5];
    const float* b_proj = (const float*)d_in[6];
    const float* a_proj = (const float*)d_in[7];
    float* outp = (float*)d_out;

    char* ws = (char*)d_ws;
    float* ksq = (float*)(ws);
    float* xsq = (float*)(ws + 16384);
    float* osq = (float*)(ws + 32768);
    char* pA  = ws + 65536;                    // 16.78 MB: Ahi -> Chi
    u16* Ahi = (u16*)pA;
    u16* Chi = (u16*)pA;                       // alias (Ahi dead after GEMM1)
    char* pWt = pA + 16777216;                 // 6.29 MB
    u16* Wthi = (u16*)pWt;
    char* pWp = pWt + 6291456;                 // 2.10 MB
    u16* Wphi = (u16*)pWp;
    char* pQ = pWp + 2097152;                  // 25.17 MB: Qb,Kb,Vt
    u16* Qb = (u16*)pQ;
    u16* Kb = (u16*)(pQ + 8388608);
    u16* Vt = (u16*)(pQ + 16777216);
    float2* ropeSC = (float2*)(pQ + 25165824); // 512 KB

    prep_kernel<<<5440, 256, 0, stream>>>(
        x, w_attn, w_proj, Ahi, Wthi, Wphi, ksq, xsq, osq, ropeSC);
    gemm1_fused<<<dim3(N3C / 128, (BATCH * TSEQ) / 128), 256, 0, stream>>>(
        Ahi, Wthi, b_attn, xsq, ksq, a_attn, ropeSC, Qb, Kb, Vt);
    attn_mfma<<<dim3(BATCH * NH, 16), 512, 0, stream>>>(Qb, Kb, Vt, Chi, osq);
    gemm_yat_mfma<<<dim3(CDIM / 64, (BATCH * TSEQ) / 64), 128, 0, stream>>>(
        Chi, Wphi, b_proj, osq, ksq + N3C, a_proj, outp,
        BATCH * TSEQ, CDIM, CDIM, (float)CDIM);
}